// Round 5
// baseline (656.412 us; speedup 1.0000x reference)
//
#include <hip/hip_runtime.h>

typedef _Float16 f16;
typedef _Float16 f16x2 __attribute__((ext_vector_type(2)));
typedef _Float16 f16x4 __attribute__((ext_vector_type(4)));
typedef _Float16 f16x8 __attribute__((ext_vector_type(8)));
typedef float f32x4 __attribute__((ext_vector_type(4)));
typedef float f32x16 __attribute__((ext_vector_type(16)));

#define MFMA16(a, b, c) __builtin_amdgcn_mfma_f32_16x16x32_f16(a, b, c, 0, 0, 0)
#define MFMA32(a, b, c) __builtin_amdgcn_mfma_f32_32x32x16_f16(a, b, c, 0, 0, 0)

__device__ __forceinline__ int swzr(int row) { return ((row & 7) << 4) ^ ((row & 8) << 2); }

// ---------------- kernel 0: convert weights to fp16 ----------------
__global__ __launch_bounds__(256) void wcvt_k(
    const float* __restrict__ tw, const float* __restrict__ pw,
    const float* __restrict__ gw, const float* __restrict__ ww,
    f16* __restrict__ Wall, f16* __restrict__ Wepi) {
  int i = blockIdx.x * 256 + threadIdx.x;
  if (i < 384 * 256) {
    int c = i >> 8, cp = i & 255;
    float v = (c < 128) ? tw[c * 256 + cp]
            : (c < 256) ? pw[(c - 128) * 256 + cp]
                        : gw[(c - 256) * 256 + cp];
    Wall[i] = (f16)v;
  }
  int j = i - 384 * 256;
  if (j >= 0 && j < 256 * 128) Wepi[j] = (f16)ww[j];
}

// ---------------- kernel 1: transpose x -> xT fp16 ----------------
__global__ __launch_bounds__(256) void xpose_k(const float* __restrict__ x,
                                               f16* __restrict__ xT) {
  __shared__ f16 t[64 * 65];
  int bx = blockIdx.x;
  int b = bx >> 8, rem = bx & 255;
  int c0 = (rem >> 6) * 64, n0 = (rem & 63) * 64;
  const float* xb = x + ((size_t)b * 256 + c0) * 4096 + n0;
#pragma unroll
  for (int rep = 0; rep < 16; ++rep) {
    int idx = rep * 256 + threadIdx.x;
    int i = idx >> 6, j = idx & 63;
    t[j * 65 + i] = (f16)xb[(size_t)i * 4096 + j];
  }
  __syncthreads();
  f16* o = xT + ((size_t)b * 4096 + n0) * 256 + c0;
#pragma unroll
  for (int rep = 0; rep < 16; ++rep) {
    int idx = rep * 256 + threadIdx.x;
    int j = idx >> 6, i = idx & 63;
    o[(size_t)j * 256 + i] = t[j * 65 + i];
  }
}

// ---------------- kernel 2: projection GEMM ----------------
__global__ __launch_bounds__(256) void proj_k(
    const f16* __restrict__ xT, const f16* __restrict__ Wall,
    const float* __restrict__ tb, const float* __restrict__ pb,
    const float* __restrict__ gb, f16* __restrict__ Q, f16* __restrict__ K,
    f16* __restrict__ Vt) {
  __shared__ f16 vs[128 * 65];
  int b = blockIdx.x >> 6, nt = blockIdx.x & 63;
  int nbase = nt * 64;
  int w = threadIdx.x >> 6, lane = threadIdx.x & 63;
  int lr = lane & 15, lhi = lane >> 4;
  int nrow = nbase + w * 16 + lr;
  const f16x8* xr = (const f16x8*)(xT + ((size_t)b * 4096 + nrow) * 256);
  f16x8 a[8];
#pragma unroll
  for (int ks = 0; ks < 8; ++ks) a[ks] = xr[ks * 4 + lhi];
  f32x4 acc[24];
#pragma unroll
  for (int ct = 0; ct < 24; ++ct) {
    acc[ct] = {0.f, 0.f, 0.f, 0.f};
    const f16x8* wr = (const f16x8*)(Wall + (size_t)(ct * 16 + lr) * 256);
#pragma unroll
    for (int ks = 0; ks < 8; ++ks) acc[ct] = MFMA16(a[ks], wr[ks * 4 + lhi], acc[ct]);
  }
  int nloc = w * 16 + lhi * 4;
#pragma unroll
  for (int ct = 0; ct < 24; ++ct) {
    int c = ct * 16 + lr;
    float bias = (c < 128) ? tb[c] : (c < 256) ? pb[c - 128] : gb[c - 256];
#pragma unroll
    for (int r = 0; r < 4; ++r) {
      float v = acc[ct][r] + bias;
      int n = nbase + nloc + r;
      if (c < 128)
        Q[((size_t)b * 4096 + n) * 128 + c] = (f16)v;
      else if (c < 256)
        K[((size_t)b * 4096 + n) * 128 + (c - 128)] = (f16)v;
      else
        vs[(c - 256) * 65 + nloc + r] = (f16)v;
    }
  }
  __syncthreads();
  f16* vo = Vt + (size_t)b * 128 * 4096 + nbase;
  for (int rep = 0; rep < 32; ++rep) {
    int idx = rep * 256 + threadIdx.x;
    int c = idx >> 6, j = idx & 63;
    vo[(size_t)c * 4096 + j] = vs[c * 65 + j];
  }
}

// ---------------- kernel 3: flash attention, KV-split-4, single-buffer LDS ----------------
// Grid 1024: b = blk&7 (one batch per XCD). Each block: 128 q-rows, kv quarter (1024).
// Single 32KB LDS buffer -> 4 blocks/CU -> 4 waves/SIMD. T14 split staging.
__global__ __launch_bounds__(256, 4) void attn_k(const f16* __restrict__ Q,
                                                 const f16* __restrict__ K,
                                                 const f16* __restrict__ Vt,
                                                 f16* __restrict__ Yp01,
                                                 f16* __restrict__ Yp23,
                                                 float2* __restrict__ ml) {
  __shared__ f16 Ks[64 * 128];
  __shared__ f16 Vs[128 * 64];
  const float L = 1.44269504f;
  int swzid = ((blockIdx.x & 7) << 7) | ((int)blockIdx.x >> 3);
  int b = swzid >> 7, rem = swzid & 127;
  int qt = rem >> 2, s = rem & 3;
  int qbase = qt * 128;
  int kvbase = s << 10;
  int tid = threadIdx.x;
  int w = tid >> 6, lane = tid & 63;
  int col = lane & 31, hi = lane >> 5;

  const f16* Qr = Q + ((size_t)b * 4096 + qbase + w * 32 + col) * 128;
  f16x8 bq[8];
#pragma unroll
  for (int ks = 0; ks < 8; ++ks) bq[ks] = *(const f16x8*)(Qr + ks * 16 + hi * 8);

  f32x16 yacc[4];
#pragma unroll
  for (int dt = 0; dt < 4; ++dt)
#pragma unroll
    for (int r = 0; r < 16; ++r) yacc[dt][r] = 0.f;
  float lv[16];
#pragma unroll
  for (int r = 0; r < 16; ++r) lv[r] = 0.f;
  float m = -1e30f, nmL = 1e30f;

  const f16* Kbase = K + (size_t)b * 4096 * 128;
  const f16* Vbase = Vt + (size_t)b * 128 * 4096;

  int krow = tid >> 4, kcolb = (tid & 15) * 16;  // K staging
  int vrow = tid >> 1, h2 = tid & 1;             // V staging
  int sv = swzr(vrow);
  int vblo[4];
#pragma unroll
  for (int u = 0; u < 4; ++u) vblo[u] = h2 * 64 + (u & 2) * 16 + (u & 1) * 8;

  // prologue: stage tile 0 (no barrier needed before first writes)
  {
    const f16* Kt = Kbase + (size_t)kvbase * 128;
    f16x8 kr[4], vr[4];
#pragma unroll
    for (int r = 0; r < 4; ++r) kr[r] = *(const f16x8*)(Kt + (r * 256 + tid) * 8);
#pragma unroll
    for (int u = 0; u < 4; ++u)
      vr[u] = *(const f16x8*)(Vbase + (size_t)vrow * 4096 + kvbase + h2 * 32 + u * 8);
#pragma unroll
    for (int r = 0; r < 4; ++r) {
      int row = r * 16 + krow;
      *(f16x8*)((char*)Ks + row * 256 + (kcolb ^ swzr(row))) = kr[r];
    }
#pragma unroll
    for (int u = 0; u < 4; ++u) {
      f16x4 lo = {vr[u][0], vr[u][1], vr[u][2], vr[u][3]};
      f16x4 hi4 = {vr[u][4], vr[u][5], vr[u][6], vr[u][7]};
      *(f16x4*)((char*)Vs + vrow * 128 + (vblo[u] ^ sv)) = lo;
      *(f16x4*)((char*)Vs + vrow * 128 + ((vblo[u] + 16) ^ sv)) = hi4;
    }
  }

  for (int t = 0; t < 16; ++t) {
    f16x8 kr[4], vr[4];
    bool pf = (t + 1 < 16);
    if (pf) {  // issue next tile's global loads early (hide under compute)
      int kv0 = kvbase + (t + 1) * 64;
      const f16* Kt = Kbase + (size_t)kv0 * 128;
#pragma unroll
      for (int r = 0; r < 4; ++r) kr[r] = *(const f16x8*)(Kt + (r * 256 + tid) * 8);
#pragma unroll
      for (int u = 0; u < 4; ++u)
        vr[u] = *(const f16x8*)(Vbase + (size_t)vrow * 4096 + kv0 + h2 * 32 + u * 8);
    }
    __syncthreads();  // tile t's LDS writes visible

    // ---- S^T = K . Q^T ----
    f32x16 s2[2];
    __builtin_amdgcn_s_setprio(1);
#pragma unroll
    for (int t2 = 0; t2 < 2; ++t2) {
#pragma unroll
      for (int r = 0; r < 16; ++r) s2[t2][r] = 0.f;
      int row = t2 * 32 + col;
      const char* kb = (const char*)Ks + row * 256;
      int sk = swzr(row);
#pragma unroll
      for (int ks = 0; ks < 8; ++ks) {
        f16x8 ak = *(const f16x8*)(kb + ((ks * 32 + hi * 16) ^ sk));
        s2[t2] = MFMA32(ak, bq[ks], s2[t2]);
      }
    }
    __builtin_amdgcn_s_setprio(0);

    // ---- per-lane online softmax (q = col) ----
    float v[16];
#pragma unroll
    for (int r = 0; r < 16; ++r) v[r] = fmaxf(s2[0][r], s2[1][r]);
    float t0 = fmaxf(fmaxf(v[0], v[1]), v[2]);
    float t1 = fmaxf(fmaxf(v[3], v[4]), v[5]);
    float t2 = fmaxf(fmaxf(v[6], v[7]), v[8]);
    float t3 = fmaxf(fmaxf(v[9], v[10]), v[11]);
    float t4 = fmaxf(fmaxf(v[12], v[13]), v[14]);
    float u0 = fmaxf(fmaxf(t0, t1), t2);
    float u1 = fmaxf(fmaxf(t3, t4), v[15]);
    float pm = fmaxf(u0, u1);
    pm = fmaxf(pm, __shfl_xor(pm, 32));
    if (pm > m + 8.f) {  // T13 defer-max
      float sc = __expf(m - pm);
      m = pm;
      nmL = -m * L;
#pragma unroll
      for (int r = 0; r < 16; ++r) lv[r] *= sc;
#pragma unroll
      for (int dt = 0; dt < 4; ++dt)
#pragma unroll
        for (int r = 0; r < 16; ++r) yacc[dt][r] *= sc;
    }
#pragma unroll
    for (int t2i = 0; t2i < 2; ++t2i)
#pragma unroll
      for (int r = 0; r < 16; ++r) s2[t2i][r] = exp2f(fmaf(s2[t2i][r], L, nmL));
#pragma unroll
    for (int r = 0; r < 16; ++r) lv[r] += s2[0][r] + s2[1][r];

    // ---- P -> f16 frags, lane-local (V columns pre-permuted) ----
    f16x8 pfr[4];
#pragma unroll
    for (int t2i = 0; t2i < 2; ++t2i)
#pragma unroll
      for (int k1 = 0; k1 < 2; ++k1) {
        f16x8 f;
#pragma unroll
        for (int c = 0; c < 8; ++c) f[c] = (f16)s2[t2i][8 * k1 + c];
        pfr[t2i * 2 + k1] = f;
      }

    // ---- Y^T += V . P ----
    __builtin_amdgcn_s_setprio(1);
#pragma unroll
    for (int kstep = 0; kstep < 4; ++kstep) {
#pragma unroll
      for (int dt = 0; dt < 4; ++dt) {
        int row = dt * 32 + col;
        f16x8 av = *(const f16x8*)((const char*)Vs + row * 128 +
                                   ((kstep * 32 + hi * 16) ^ swzr(row)));
        yacc[dt] = MFMA32(av, pfr[kstep], yacc[dt]);
      }
    }
    __builtin_amdgcn_s_setprio(0);

    __syncthreads();  // everyone done reading tile t
    if (pf) {         // write tile t+1 (T14 write-late)
#pragma unroll
      for (int r = 0; r < 4; ++r) {
        int row = r * 16 + krow;
        *(f16x8*)((char*)Ks + row * 256 + (kcolb ^ swzr(row))) = kr[r];
      }
#pragma unroll
      for (int u = 0; u < 4; ++u) {
        f16x4 lo = {vr[u][0], vr[u][1], vr[u][2], vr[u][3]};
        f16x4 hi4 = {vr[u][4], vr[u][5], vr[u][6], vr[u][7]};
        *(f16x4*)((char*)Vs + vrow * 128 + (vblo[u] ^ sv)) = lo;
        *(f16x4*)((char*)Vs + vrow * 128 + ((vblo[u] + 16) ^ sv)) = hi4;
      }
    }
  }

  // final l reduce (lane-partial -> scalar)
  float l8[8], l4[4];
#pragma unroll
  for (int i = 0; i < 8; ++i) l8[i] = lv[i] + lv[i + 8];
#pragma unroll
  for (int i = 0; i < 4; ++i) l4[i] = l8[i] + l8[i + 4];
  float l = (l4[0] + l4[1]) + (l4[2] + l4[3]);
  l += __shfl_xor(l, 32);

  int rowG = b * 4096 + qbase + w * 32 + col;
  f16* yo = (s < 2 ? Yp01 : Yp23) + ((size_t)(s & 1) * 32768 + rowG) * 128;
  float inv = 1.0f / l;
#pragma unroll
  for (int dt = 0; dt < 4; ++dt)
#pragma unroll
    for (int a = 0; a < 4; ++a) {
      f16x4 ov = {(f16)(yacc[dt][4 * a] * inv), (f16)(yacc[dt][4 * a + 1] * inv),
                  (f16)(yacc[dt][4 * a + 2] * inv), (f16)(yacc[dt][4 * a + 3] * inv)};
      *(f16x4*)(yo + dt * 32 + a * 8 + hi * 4) = ov;
    }
  if (hi == 0) ml[s * 32768 + rowG] = make_float2(m, l);
}

// ---------------- kernel 4: 4-way combine + epilogue GEMM + bias + residual ----------------
__global__ __launch_bounds__(256) void epi_k(const f16* __restrict__ Yp01,
                                             const f16* __restrict__ Yp23,
                                             const float2* __restrict__ ml,
                                             const f16* __restrict__ Wepi,
                                             const float* __restrict__ Wb,
                                             const float* __restrict__ x,
                                             float* __restrict__ out) {
  int b = blockIdx.x >> 6, nt = blockIdx.x & 63;
  int nbase = nt * 64;
  int w = threadIdx.x >> 6, lane = threadIdx.x & 63;
  int lr = lane & 15, lhi = lane >> 4;
  const f16* yb0 = Yp01;
  const f16* yb1 = Yp01 + (size_t)32768 * 128;
  const f16* yb2 = Yp23;
  const f16* yb3 = Yp23 + (size_t)32768 * 128;
  f16x8 by[4][4];
#pragma unroll
  for (int n4 = 0; n4 < 4; ++n4) {
    int row = b * 4096 + nbase + n4 * 16 + lr;
    float2 m0 = ml[row], m1 = ml[32768 + row], m2 = ml[65536 + row], m3 = ml[98304 + row];
    float mm = fmaxf(fmaxf(m0.x, m1.x), fmaxf(m2.x, m3.x));
    float w0 = m0.y * __expf(m0.x - mm), w1 = m1.y * __expf(m1.x - mm);
    float w2 = m2.y * __expf(m2.x - mm), w3 = m3.y * __expf(m3.x - mm);
    float inv = 1.f / (w0 + w1 + w2 + w3);
    w0 *= inv; w1 *= inv; w2 *= inv; w3 *= inv;
    size_t rb = (size_t)row * 128;
#pragma unroll
    for (int ks = 0; ks < 4; ++ks) {
      int eo = ks * 32 + lhi * 8;
      f16x8 a0 = *(const f16x8*)(yb0 + rb + eo);
      f16x8 a1 = *(const f16x8*)(yb1 + rb + eo);
      f16x8 a2 = *(const f16x8*)(yb2 + rb + eo);
      f16x8 a3 = *(const f16x8*)(yb3 + rb + eo);
      f16x8 o;
#pragma unroll
      for (int e = 0; e < 8; ++e)
        o[e] = (f16)(w0 * (float)a0[e] + w1 * (float)a1[e] + w2 * (float)a2[e] +
                     w3 * (float)a3[e]);
      by[n4][ks] = o;
    }
  }
#pragma unroll
  for (int ot = 0; ot < 4; ++ot) {
    int o0 = w * 64 + ot * 16;
    const f16x8* wr = (const f16x8*)(Wepi + (size_t)(o0 + lr) * 128);
    f16x8 a[4];
#pragma unroll
    for (int ks = 0; ks < 4; ++ks) a[ks] = wr[ks * 4 + lhi];
#pragma unroll
    for (int n4 = 0; n4 < 4; ++n4) {
      f32x4 acc = {0.f, 0.f, 0.f, 0.f};
#pragma unroll
      for (int ks = 0; ks < 4; ++ks) acc = MFMA16(a[ks], by[n4][ks], acc);
#pragma unroll
      for (int r = 0; r < 4; ++r) {
        int o = o0 + lhi * 4 + r;
        int n = nbase + n4 * 16 + lr;
        size_t idx = ((size_t)b * 256 + o) * 4096 + n;
        out[idx] = x[idx] + Wb[o] + acc[r];
      }
    }
  }
}

extern "C" void kernel_launch(void* const* d_in, const int* in_sizes, int n_in,
                              void* d_out, int out_size, void* d_ws, size_t ws_size,
                              hipStream_t stream) {
  const float* x       = (const float*)d_in[0];
  const float* g_w     = (const float*)d_in[1];
  const float* g_b     = (const float*)d_in[2];
  const float* theta_w = (const float*)d_in[3];
  const float* theta_b = (const float*)d_in[4];
  const float* phi_w   = (const float*)d_in[5];
  const float* phi_b   = (const float*)d_in[6];
  const float* W_w     = (const float*)d_in[7];
  const float* W_b     = (const float*)d_in[8];
  float* out = (float*)d_out;

  f16* xT   = (f16*)d_ws;                       // [8,4096,256] 16MB; reused as Yp01 (splits 0,1)
  f16* Q    = xT + (size_t)8 * 4096 * 256;      // 8MB
  f16* Kk   = Q + (size_t)8 * 4096 * 128;       // 8MB
  f16* Vt   = Kk + (size_t)8 * 4096 * 128;      // 8MB
  f16* Wall = Vt + (size_t)8 * 4096 * 128;      // [384,256]
  f16* Wepi = Wall + 384 * 256;                 // [256,128]
  float2* ml = (float2*)(Wepi + 256 * 128);     // [4][32768] = 1MB
  f16* Yp23 = (f16*)(ml + 4 * 32768);           // splits 2,3 = 16MB  (ws total ~57.3MB)
  f16* Yp01 = xT;

  wcvt_k<<<512, 256, 0, stream>>>(theta_w, phi_w, g_w, W_w, Wall, Wepi);
  xpose_k<<<2048, 256, 0, stream>>>(x, xT);
  proj_k<<<512, 256, 0, stream>>>(xT, Wall, theta_b, phi_b, g_b, Q, Kk, Vt);
  attn_k<<<1024, 256, 0, stream>>>(Q, Kk, Vt, Yp01, Yp23, ml);
  epi_k<<<512, 256, 0, stream>>>(Yp01, Yp23, ml, Wepi, W_b, x, out);
}

// Round 6
// 196.663 us; speedup vs baseline: 3.3378x; 3.3378x over previous
//
#include <hip/hip_runtime.h>

typedef _Float16 f16;
typedef _Float16 f16x2 __attribute__((ext_vector_type(2)));
typedef _Float16 f16x4 __attribute__((ext_vector_type(4)));
typedef _Float16 f16x8 __attribute__((ext_vector_type(8)));
typedef float f32x4 __attribute__((ext_vector_type(4)));
typedef float f32x16 __attribute__((ext_vector_type(16)));

#define MFMA16(a, b, c) __builtin_amdgcn_mfma_f32_16x16x32_f16(a, b, c, 0, 0, 0)
#define MFMA32(a, b, c) __builtin_amdgcn_mfma_f32_32x32x16_f16(a, b, c, 0, 0, 0)

__device__ __forceinline__ int swzr(int row) { return ((row & 7) << 4) ^ ((row & 8) << 2); }

// ---------------- kernel 0: convert weights to fp16 ----------------
__global__ __launch_bounds__(256) void wcvt_k(
    const float* __restrict__ tw, const float* __restrict__ pw,
    const float* __restrict__ gw, const float* __restrict__ ww,
    f16* __restrict__ Wall, f16* __restrict__ Wepi) {
  int i = blockIdx.x * 256 + threadIdx.x;
  if (i < 384 * 256) {
    int c = i >> 8, cp = i & 255;
    float v = (c < 128) ? tw[c * 256 + cp]
            : (c < 256) ? pw[(c - 128) * 256 + cp]
                        : gw[(c - 256) * 256 + cp];
    Wall[i] = (f16)v;
  }
  int j = i - 384 * 256;
  if (j >= 0 && j < 256 * 128) Wepi[j] = (f16)ww[j];
}

// ---------------- kernel 1: transpose x -> xT fp16 ----------------
__global__ __launch_bounds__(256) void xpose_k(const float* __restrict__ x,
                                               f16* __restrict__ xT) {
  __shared__ f16 t[64 * 65];
  int bx = blockIdx.x;
  int b = bx >> 8, rem = bx & 255;
  int c0 = (rem >> 6) * 64, n0 = (rem & 63) * 64;
  const float* xb = x + ((size_t)b * 256 + c0) * 4096 + n0;
#pragma unroll
  for (int rep = 0; rep < 16; ++rep) {
    int idx = rep * 256 + threadIdx.x;
    int i = idx >> 6, j = idx & 63;
    t[j * 65 + i] = (f16)xb[(size_t)i * 4096 + j];
  }
  __syncthreads();
  f16* o = xT + ((size_t)b * 4096 + n0) * 256 + c0;
#pragma unroll
  for (int rep = 0; rep < 16; ++rep) {
    int idx = rep * 256 + threadIdx.x;
    int j = idx >> 6, i = idx & 63;
    o[(size_t)j * 256 + i] = t[j * 65 + i];
  }
}

// ---------------- kernel 2: projection GEMM ----------------
__global__ __launch_bounds__(256) void proj_k(
    const f16* __restrict__ xT, const f16* __restrict__ Wall,
    const float* __restrict__ tb, const float* __restrict__ pb,
    const float* __restrict__ gb, f16* __restrict__ Q, f16* __restrict__ K,
    f16* __restrict__ Vt) {
  __shared__ f16 vs[128 * 65];
  int b = blockIdx.x >> 6, nt = blockIdx.x & 63;
  int nbase = nt * 64;
  int w = threadIdx.x >> 6, lane = threadIdx.x & 63;
  int lr = lane & 15, lhi = lane >> 4;
  int nrow = nbase + w * 16 + lr;
  const f16x8* xr = (const f16x8*)(xT + ((size_t)b * 4096 + nrow) * 256);
  f16x8 a[8];
#pragma unroll
  for (int ks = 0; ks < 8; ++ks) a[ks] = xr[ks * 4 + lhi];
  f32x4 acc[24];
#pragma unroll
  for (int ct = 0; ct < 24; ++ct) {
    acc[ct] = {0.f, 0.f, 0.f, 0.f};
    const f16x8* wr = (const f16x8*)(Wall + (size_t)(ct * 16 + lr) * 256);
#pragma unroll
    for (int ks = 0; ks < 8; ++ks) acc[ct] = MFMA16(a[ks], wr[ks * 4 + lhi], acc[ct]);
  }
  int nloc = w * 16 + lhi * 4;
#pragma unroll
  for (int ct = 0; ct < 24; ++ct) {
    int c = ct * 16 + lr;
    float bias = (c < 128) ? tb[c] : (c < 256) ? pb[c - 128] : gb[c - 256];
#pragma unroll
    for (int r = 0; r < 4; ++r) {
      float v = acc[ct][r] + bias;
      int n = nbase + nloc + r;
      if (c < 128)
        Q[((size_t)b * 4096 + n) * 128 + c] = (f16)v;
      else if (c < 256)
        K[((size_t)b * 4096 + n) * 128 + (c - 128)] = (f16)v;
      else
        vs[(c - 256) * 65 + nloc + r] = (f16)v;
    }
  }
  __syncthreads();
  f16* vo = Vt + (size_t)b * 128 * 4096 + nbase;
  for (int rep = 0; rep < 32; ++rep) {
    int idx = rep * 256 + threadIdx.x;
    int c = idx >> 6, j = idx & 63;
    vo[(size_t)c * 4096 + j] = vs[c * 65 + j];
  }
}

// ---------------- kernel 3: flash attention, KV-split-4, single-buffer LDS ----------------
// Grid 1024: b = blk&7 (one batch per XCD). Each block: 128 q-rows, kv quarter (1024).
// 32KB LDS -> 4 blocks/CU (reg-limited). NO tight launch-bounds: R5's (256,4) capped
// unified VGPR at 128 -> 64 arch VGPRs -> scratch spill -> 2.3GB HBM traffic, 6x slower.
__global__ __launch_bounds__(256, 2) void attn_k(const f16* __restrict__ Q,
                                                 const f16* __restrict__ K,
                                                 const f16* __restrict__ Vt,
                                                 f16* __restrict__ Yp01,
                                                 f16* __restrict__ Yp23,
                                                 float2* __restrict__ ml) {
  __shared__ f16 Ks[64 * 128];
  __shared__ f16 Vs[128 * 64];
  const float L = 1.44269504f;
  int swzid = ((blockIdx.x & 7) << 7) | ((int)blockIdx.x >> 3);
  int b = swzid >> 7, rem = swzid & 127;
  int qt = rem >> 2, s = rem & 3;
  int qbase = qt * 128;
  int kvbase = s << 10;
  int tid = threadIdx.x;
  int w = tid >> 6, lane = tid & 63;
  int col = lane & 31, hi = lane >> 5;

  const f16* Qr = Q + ((size_t)b * 4096 + qbase + w * 32 + col) * 128;
  f16x8 bq[8];
#pragma unroll
  for (int ks = 0; ks < 8; ++ks) bq[ks] = *(const f16x8*)(Qr + ks * 16 + hi * 8);

  f32x16 yacc[4];
#pragma unroll
  for (int dt = 0; dt < 4; ++dt)
#pragma unroll
    for (int r = 0; r < 16; ++r) yacc[dt][r] = 0.f;
  float lv[16];
#pragma unroll
  for (int r = 0; r < 16; ++r) lv[r] = 0.f;
  float m = -1e30f, nmL = 1e30f;

  const f16* Kbase = K + (size_t)b * 4096 * 128;
  const f16* Vbase = Vt + (size_t)b * 128 * 4096;

  int krow = tid >> 4, kcolb = (tid & 15) * 16;  // K staging
  int vrow = tid >> 1, h2 = tid & 1;             // V staging
  int sv = swzr(vrow);
  int vblo[4];
#pragma unroll
  for (int u = 0; u < 4; ++u) vblo[u] = h2 * 64 + (u & 2) * 16 + (u & 1) * 8;

  // prologue: stage tile 0 (no barrier needed before first writes)
  {
    const f16* Kt = Kbase + (size_t)kvbase * 128;
    f16x8 kr[4], vr[4];
#pragma unroll
    for (int r = 0; r < 4; ++r) kr[r] = *(const f16x8*)(Kt + (r * 256 + tid) * 8);
#pragma unroll
    for (int u = 0; u < 4; ++u)
      vr[u] = *(const f16x8*)(Vbase + (size_t)vrow * 4096 + kvbase + h2 * 32 + u * 8);
#pragma unroll
    for (int r = 0; r < 4; ++r) {
      int row = r * 16 + krow;
      *(f16x8*)((char*)Ks + row * 256 + (kcolb ^ swzr(row))) = kr[r];
    }
#pragma unroll
    for (int u = 0; u < 4; ++u) {
      f16x4 lo = {vr[u][0], vr[u][1], vr[u][2], vr[u][3]};
      f16x4 hi4 = {vr[u][4], vr[u][5], vr[u][6], vr[u][7]};
      *(f16x4*)((char*)Vs + vrow * 128 + (vblo[u] ^ sv)) = lo;
      *(f16x4*)((char*)Vs + vrow * 128 + ((vblo[u] + 16) ^ sv)) = hi4;
    }
  }

  for (int t = 0; t < 16; ++t) {
    f16x8 kr[4], vr[4];
    bool pf = (t + 1 < 16);
    if (pf) {  // issue next tile's global loads early (hide under compute)
      int kv0 = kvbase + (t + 1) * 64;
      const f16* Kt = Kbase + (size_t)kv0 * 128;
#pragma unroll
      for (int r = 0; r < 4; ++r) kr[r] = *(const f16x8*)(Kt + (r * 256 + tid) * 8);
#pragma unroll
      for (int u = 0; u < 4; ++u)
        vr[u] = *(const f16x8*)(Vbase + (size_t)vrow * 4096 + kv0 + h2 * 32 + u * 8);
    }
    __syncthreads();  // tile t's LDS writes visible

    // ---- S^T = K . Q^T ----
    f32x16 s2[2];
    __builtin_amdgcn_s_setprio(1);
#pragma unroll
    for (int t2 = 0; t2 < 2; ++t2) {
#pragma unroll
      for (int r = 0; r < 16; ++r) s2[t2][r] = 0.f;
      int row = t2 * 32 + col;
      const char* kb = (const char*)Ks + row * 256;
      int sk = swzr(row);
#pragma unroll
      for (int ks = 0; ks < 8; ++ks) {
        f16x8 ak = *(const f16x8*)(kb + ((ks * 32 + hi * 16) ^ sk));
        s2[t2] = MFMA32(ak, bq[ks], s2[t2]);
      }
    }
    __builtin_amdgcn_s_setprio(0);

    // ---- per-lane online softmax (q = col) ----
    float v[16];
#pragma unroll
    for (int r = 0; r < 16; ++r) v[r] = fmaxf(s2[0][r], s2[1][r]);
    float t0 = fmaxf(fmaxf(v[0], v[1]), v[2]);
    float t1 = fmaxf(fmaxf(v[3], v[4]), v[5]);
    float t2 = fmaxf(fmaxf(v[6], v[7]), v[8]);
    float t3 = fmaxf(fmaxf(v[9], v[10]), v[11]);
    float t4 = fmaxf(fmaxf(v[12], v[13]), v[14]);
    float u0 = fmaxf(fmaxf(t0, t1), t2);
    float u1 = fmaxf(fmaxf(t3, t4), v[15]);
    float pm = fmaxf(u0, u1);
    pm = fmaxf(pm, __shfl_xor(pm, 32));
    if (pm > m + 8.f) {  // T13 defer-max
      float sc = __expf(m - pm);
      m = pm;
      nmL = -m * L;
#pragma unroll
      for (int r = 0; r < 16; ++r) lv[r] *= sc;
#pragma unroll
      for (int dt = 0; dt < 4; ++dt)
#pragma unroll
        for (int r = 0; r < 16; ++r) yacc[dt][r] *= sc;
    }
#pragma unroll
    for (int t2i = 0; t2i < 2; ++t2i)
#pragma unroll
      for (int r = 0; r < 16; ++r) s2[t2i][r] = exp2f(fmaf(s2[t2i][r], L, nmL));
#pragma unroll
    for (int r = 0; r < 16; ++r) lv[r] += s2[0][r] + s2[1][r];

    // ---- P -> f16 frags, lane-local (V columns pre-permuted) ----
    f16x8 pfr[4];
#pragma unroll
    for (int t2i = 0; t2i < 2; ++t2i)
#pragma unroll
      for (int k1 = 0; k1 < 2; ++k1) {
        f16x8 f;
#pragma unroll
        for (int c = 0; c < 8; ++c) f[c] = (f16)s2[t2i][8 * k1 + c];
        pfr[t2i * 2 + k1] = f;
      }

    // ---- Y^T += V . P ----
    __builtin_amdgcn_s_setprio(1);
#pragma unroll
    for (int kstep = 0; kstep < 4; ++kstep) {
#pragma unroll
      for (int dt = 0; dt < 4; ++dt) {
        int row = dt * 32 + col;
        f16x8 av = *(const f16x8*)((const char*)Vs + row * 128 +
                                   ((kstep * 32 + hi * 16) ^ swzr(row)));
        yacc[dt] = MFMA32(av, pfr[kstep], yacc[dt]);
      }
    }
    __builtin_amdgcn_s_setprio(0);

    __syncthreads();  // everyone done reading tile t
    if (pf) {         // write tile t+1 (T14 write-late)
#pragma unroll
      for (int r = 0; r < 4; ++r) {
        int row = r * 16 + krow;
        *(f16x8*)((char*)Ks + row * 256 + (kcolb ^ swzr(row))) = kr[r];
      }
#pragma unroll
      for (int u = 0; u < 4; ++u) {
        f16x4 lo = {vr[u][0], vr[u][1], vr[u][2], vr[u][3]};
        f16x4 hi4 = {vr[u][4], vr[u][5], vr[u][6], vr[u][7]};
        *(f16x4*)((char*)Vs + vrow * 128 + (vblo[u] ^ sv)) = lo;
        *(f16x4*)((char*)Vs + vrow * 128 + ((vblo[u] + 16) ^ sv)) = hi4;
      }
    }
  }

  // final l reduce (lane-partial -> scalar)
  float l8[8], l4[4];
#pragma unroll
  for (int i = 0; i < 8; ++i) l8[i] = lv[i] + lv[i + 8];
#pragma unroll
  for (int i = 0; i < 4; ++i) l4[i] = l8[i] + l8[i + 4];
  float l = (l4[0] + l4[1]) + (l4[2] + l4[3]);
  l += __shfl_xor(l, 32);

  int rowG = b * 4096 + qbase + w * 32 + col;
  f16* yo = (s < 2 ? Yp01 : Yp23) + ((size_t)(s & 1) * 32768 + rowG) * 128;
  float inv = 1.0f / l;
#pragma unroll
  for (int dt = 0; dt < 4; ++dt)
#pragma unroll
    for (int a = 0; a < 4; ++a) {
      f16x4 ov = {(f16)(yacc[dt][4 * a] * inv), (f16)(yacc[dt][4 * a + 1] * inv),
                  (f16)(yacc[dt][4 * a + 2] * inv), (f16)(yacc[dt][4 * a + 3] * inv)};
      *(f16x4*)(yo + dt * 32 + a * 8 + hi * 4) = ov;
    }
  if (hi == 0) ml[s * 32768 + rowG] = make_float2(m, l);
}

// ---------------- kernel 4: 4-way combine + epilogue GEMM + bias + residual ----------------
__global__ __launch_bounds__(256) void epi_k(const f16* __restrict__ Yp01,
                                             const f16* __restrict__ Yp23,
                                             const float2* __restrict__ ml,
                                             const f16* __restrict__ Wepi,
                                             const float* __restrict__ Wb,
                                             const float* __restrict__ x,
                                             float* __restrict__ out) {
  int b = blockIdx.x >> 6, nt = blockIdx.x & 63;
  int nbase = nt * 64;
  int w = threadIdx.x >> 6, lane = threadIdx.x & 63;
  int lr = lane & 15, lhi = lane >> 4;
  const f16* yb0 = Yp01;
  const f16* yb1 = Yp01 + (size_t)32768 * 128;
  const f16* yb2 = Yp23;
  const f16* yb3 = Yp23 + (size_t)32768 * 128;
  f16x8 by[4][4];
#pragma unroll
  for (int n4 = 0; n4 < 4; ++n4) {
    int row = b * 4096 + nbase + n4 * 16 + lr;
    float2 m0 = ml[row], m1 = ml[32768 + row], m2 = ml[65536 + row], m3 = ml[98304 + row];
    float mm = fmaxf(fmaxf(m0.x, m1.x), fmaxf(m2.x, m3.x));
    float w0 = m0.y * __expf(m0.x - mm), w1 = m1.y * __expf(m1.x - mm);
    float w2 = m2.y * __expf(m2.x - mm), w3 = m3.y * __expf(m3.x - mm);
    float inv = 1.f / (w0 + w1 + w2 + w3);
    w0 *= inv; w1 *= inv; w2 *= inv; w3 *= inv;
    size_t rb = (size_t)row * 128;
#pragma unroll
    for (int ks = 0; ks < 4; ++ks) {
      int eo = ks * 32 + lhi * 8;
      f16x8 a0 = *(const f16x8*)(yb0 + rb + eo);
      f16x8 a1 = *(const f16x8*)(yb1 + rb + eo);
      f16x8 a2 = *(const f16x8*)(yb2 + rb + eo);
      f16x8 a3 = *(const f16x8*)(yb3 + rb + eo);
      f16x8 o;
#pragma unroll
      for (int e = 0; e < 8; ++e)
        o[e] = (f16)(w0 * (float)a0[e] + w1 * (float)a1[e] + w2 * (float)a2[e] +
                     w3 * (float)a3[e]);
      by[n4][ks] = o;
    }
  }
#pragma unroll
  for (int ot = 0; ot < 4; ++ot) {
    int o0 = w * 64 + ot * 16;
    const f16x8* wr = (const f16x8*)(Wepi + (size_t)(o0 + lr) * 128);
    f16x8 a[4];
#pragma unroll
    for (int ks = 0; ks < 4; ++ks) a[ks] = wr[ks * 4 + lhi];
#pragma unroll
    for (int n4 = 0; n4 < 4; ++n4) {
      f32x4 acc = {0.f, 0.f, 0.f, 0.f};
#pragma unroll
      for (int ks = 0; ks < 4; ++ks) acc = MFMA16(a[ks], by[n4][ks], acc);
#pragma unroll
      for (int r = 0; r < 4; ++r) {
        int o = o0 + lhi * 4 + r;
        int n = nbase + n4 * 16 + lr;
        size_t idx = ((size_t)b * 256 + o) * 4096 + n;
        out[idx] = x[idx] + Wb[o] + acc[r];
      }
    }
  }
}

extern "C" void kernel_launch(void* const* d_in, const int* in_sizes, int n_in,
                              void* d_out, int out_size, void* d_ws, size_t ws_size,
                              hipStream_t stream) {
  const float* x       = (const float*)d_in[0];
  const float* g_w     = (const float*)d_in[1];
  const float* g_b     = (const float*)d_in[2];
  const float* theta_w = (const float*)d_in[3];
  const float* theta_b = (const float*)d_in[4];
  const float* phi_w   = (const float*)d_in[5];
  const float* phi_b   = (const float*)d_in[6];
  const float* W_w     = (const float*)d_in[7];
  const float* W_b     = (const float*)d_in[8];
  float* out = (float*)d_out;

  f16* xT   = (f16*)d_ws;                       // [8,4096,256] 16MB; reused as Yp01 (splits 0,1)
  f16* Q    = xT + (size_t)8 * 4096 * 256;      // 8MB
  f16* Kk   = Q + (size_t)8 * 4096 * 128;       // 8MB
  f16* Vt   = Kk + (size_t)8 * 4096 * 128;      // 8MB
  f16* Wall = Vt + (size_t)8 * 4096 * 128;      // [384,256]
  f16* Wepi = Wall + 384 * 256;                 // [256,128]
  float2* ml = (float2*)(Wepi + 256 * 128);     // [4][32768] = 1MB
  f16* Yp23 = (f16*)(ml + 4 * 32768);           // splits 2,3 = 16MB  (ws total ~57.3MB)
  f16* Yp01 = xT;

  wcvt_k<<<512, 256, 0, stream>>>(theta_w, phi_w, g_w, W_w, Wall, Wepi);
  xpose_k<<<2048, 256, 0, stream>>>(x, xT);
  proj_k<<<512, 256, 0, stream>>>(xT, Wall, theta_b, phi_b, g_b, Q, Kk, Vt);
  attn_k<<<1024, 256, 0, stream>>>(Q, Kk, Vt, Yp01, Yp23, ml);
  epi_k<<<512, 256, 0, stream>>>(Yp01, Yp23, ml, Wepi, W_b, x, out);
}

// Round 8
// 186.911 us; speedup vs baseline: 3.5119x; 1.0522x over previous
//
#include <hip/hip_runtime.h>

typedef _Float16 f16;
typedef _Float16 f16x4 __attribute__((ext_vector_type(4)));
typedef _Float16 f16x8 __attribute__((ext_vector_type(8)));
typedef float f32x4 __attribute__((ext_vector_type(4)));
typedef float f32x16 __attribute__((ext_vector_type(16)));

#define MFMA16(a, b, c) __builtin_amdgcn_mfma_f32_16x16x32_f16(a, b, c, 0, 0, 0)
#define MFMA32(a, b, c) __builtin_amdgcn_mfma_f32_32x32x16_f16(a, b, c, 0, 0, 0)

__device__ __forceinline__ int swzr(int row) { return ((row & 7) << 4) ^ ((row & 8) << 2); }

// ---------------- kernel 0: convert weights to fp16 ----------------
__global__ __launch_bounds__(256) void wcvt_k(
    const float* __restrict__ tw, const float* __restrict__ pw,
    const float* __restrict__ gw, const float* __restrict__ ww,
    f16* __restrict__ Wall, f16* __restrict__ Wepi) {
  int i = blockIdx.x * 256 + threadIdx.x;
  if (i < 384 * 256) {
    int c = i >> 8, cp = i & 255;
    float v = (c < 128) ? tw[c * 256 + cp]
            : (c < 256) ? pw[(c - 128) * 256 + cp]
                        : gw[(c - 256) * 256 + cp];
    Wall[i] = (f16)v;
  }
  int j = i - 384 * 256;
  if (j >= 0 && j < 256 * 128) Wepi[j] = (f16)ww[j];
}

// ---------------- kernel 1: projection GEMM, reads x natively ----------------
// x [B,256,4096] fp32 staged per block as xs[64 n][256 k] f16 via 4x4 register
// transpose (replaces the separate xpose kernel + 128MB xT round-trip).
__global__ __launch_bounds__(256) void proj_k(
    const float* __restrict__ x, const f16* __restrict__ Wall,
    const float* __restrict__ tb, const float* __restrict__ pb,
    const float* __restrict__ gb, f16* __restrict__ Q, f16* __restrict__ K,
    f16* __restrict__ Vt) {
  __shared__ f16 xs[64 * 264];  // row stride 264 f16 = 33*16B -> slot rotate 1/row
  __shared__ f16 vs[128 * 65];
  int b = blockIdx.x >> 6, nt = blockIdx.x & 63;
  int nbase = nt * 64;
  int tid = threadIdx.x;

  // stage: thread handles 4 passes of a 4k x 4n block
  int nq = tid & 15, kq0 = tid >> 4;
#pragma unroll
  for (int p = 0; p < 4; ++p) {
    int kq = kq0 + 16 * p;
    float4 ld[4];
#pragma unroll
    for (int j = 0; j < 4; ++j)
      ld[j] = *(const float4*)(x + ((size_t)b * 256 + 4 * kq + j) * 4096 + nbase + 4 * nq);
#pragma unroll
    for (int e = 0; e < 4; ++e) {
      f16x4 wv = {(f16)((&ld[0].x)[e]), (f16)((&ld[1].x)[e]), (f16)((&ld[2].x)[e]),
                  (f16)((&ld[3].x)[e])};
      *(f16x4*)(&xs[(4 * nq + e) * 264 + 4 * kq]) = wv;
    }
  }
  __syncthreads();

  int w = tid >> 6, lane = tid & 63;
  int lr = lane & 15, lhi = lane >> 4;
  f16x8 a[8];
#pragma unroll
  for (int ks = 0; ks < 8; ++ks)
    a[ks] = *(const f16x8*)(&xs[(w * 16 + lr) * 264 + ks * 32 + lhi * 8]);
  f32x4 acc[24];
#pragma unroll
  for (int ct = 0; ct < 24; ++ct) {
    acc[ct] = {0.f, 0.f, 0.f, 0.f};
    const f16x8* wr = (const f16x8*)(Wall + (size_t)(ct * 16 + lr) * 256);
#pragma unroll
    for (int ks = 0; ks < 8; ++ks) acc[ct] = MFMA16(a[ks], wr[ks * 4 + lhi], acc[ct]);
  }
  int nloc = w * 16 + lhi * 4;
#pragma unroll
  for (int ct = 0; ct < 24; ++ct) {
    int c = ct * 16 + lr;
    float bias = (c < 128) ? tb[c] : (c < 256) ? pb[c - 128] : gb[c - 256];
#pragma unroll
    for (int r = 0; r < 4; ++r) {
      float v = acc[ct][r] + bias;
      int n = nbase + nloc + r;
      if (c < 128)
        Q[((size_t)b * 4096 + n) * 128 + c] = (f16)v;
      else if (c < 256)
        K[((size_t)b * 4096 + n) * 128 + (c - 128)] = (f16)v;
      else
        vs[(c - 256) * 65 + nloc + r] = (f16)v;
    }
  }
  __syncthreads();
  f16* vo = Vt + (size_t)b * 128 * 4096 + nbase;
  for (int rep = 0; rep < 32; ++rep) {
    int idx = rep * 256 + threadIdx.x;
    int c = idx >> 6, j = idx & 63;
    vo[(size_t)c * 4096 + j] = vs[c * 65 + j];
  }
}

// ---------------- kernel 2: flash attention, KV-split-2, dbuf, b128 V staging ----
// V kv-permute (bit2<->3 within 16-groups) done IN REGISTERS, written as 4x
// ds_write_b128 (R4-R6 used 8x interleaved b64 -> the 1.05e7 bank conflicts).
__global__ __launch_bounds__(256, 2) void attn_k(const f16* __restrict__ Q,
                                                 const f16* __restrict__ K,
                                                 const f16* __restrict__ Vt,
                                                 f16* __restrict__ Yp,
                                                 float2* __restrict__ ml) {
  __shared__ f16 Ks[2][64 * 128];
  __shared__ f16 Vs[2][128 * 64];
  const float L = 1.44269504f;
  int swzid = ((blockIdx.x & 7) << 6) | ((int)blockIdx.x >> 3);
  int b = swzid >> 6, rem = swzid & 63;
  int qt = rem >> 1, half = rem & 1;
  int qbase = qt * 128;
  int kvbase = half << 11;
  int tid = threadIdx.x;
  int w = tid >> 6, lane = tid & 63;
  int col = lane & 31, hi = lane >> 5;

  const f16* Qr = Q + ((size_t)b * 4096 + qbase + w * 32 + col) * 128;
  f16x8 bq[8];
#pragma unroll
  for (int ks = 0; ks < 8; ++ks) bq[ks] = *(const f16x8*)(Qr + ks * 16 + hi * 8);

  f32x16 yacc[4];
#pragma unroll
  for (int dt = 0; dt < 4; ++dt)
#pragma unroll
    for (int r = 0; r < 16; ++r) yacc[dt][r] = 0.f;
  float lv[16];
#pragma unroll
  for (int r = 0; r < 16; ++r) lv[r] = 0.f;
  float m = -1e30f, nmL = 1e30f;

  const f16* Kbase = K + (size_t)b * 4096 * 128;
  const f16* Vbase = Vt + (size_t)b * 128 * 4096;

  int krow = tid >> 4, kcolb = (tid & 15) * 16;  // K staging
  int vrow = tid >> 1, h2 = tid & 1;             // V staging
  int sv = swzr(vrow);

  // prologue: stage tile 0 into buffer 0
  {
    const f16* Kt = Kbase + (size_t)kvbase * 128;
    f16x8 kr[4], vr[4];
#pragma unroll
    for (int r = 0; r < 4; ++r) kr[r] = *(const f16x8*)(Kt + (r * 256 + tid) * 8);
#pragma unroll
    for (int u = 0; u < 4; ++u)
      vr[u] = *(const f16x8*)(Vbase + (size_t)vrow * 4096 + kvbase + h2 * 32 + u * 8);
#pragma unroll
    for (int r = 0; r < 4; ++r) {
      int row = r * 16 + krow;
      *(f16x8*)((char*)Ks[0] + row * 256 + (kcolb ^ swzr(row))) = kr[r];
    }
    f16x8 c0, c1, c2, c3;
#pragma unroll
    for (int e = 0; e < 4; ++e) {
      c0[e] = vr[0][e];     c0[4 + e] = vr[1][e];
      c1[e] = vr[0][4 + e]; c1[4 + e] = vr[1][4 + e];
      c2[e] = vr[2][e];     c2[4 + e] = vr[3][e];
      c3[e] = vr[2][4 + e]; c3[4 + e] = vr[3][4 + e];
    }
    char* vb = (char*)Vs[0] + vrow * 128;
    *(f16x8*)(vb + ((h2 * 64 + 0) ^ sv)) = c0;
    *(f16x8*)(vb + ((h2 * 64 + 16) ^ sv)) = c1;
    *(f16x8*)(vb + ((h2 * 64 + 32) ^ sv)) = c2;
    *(f16x8*)(vb + ((h2 * 64 + 48) ^ sv)) = c3;
  }

  for (int t = 0; t < 32; ++t) {
    int cur = t & 1, nxt = cur ^ 1;
    f16x8 kr[4], vr[4];
    bool pf = (t + 1 < 32);
    if (pf) {  // issue next tile's global loads early
      int kv0 = kvbase + (t + 1) * 64;
      const f16* Kt = Kbase + (size_t)kv0 * 128;
#pragma unroll
      for (int r = 0; r < 4; ++r) kr[r] = *(const f16x8*)(Kt + (r * 256 + tid) * 8);
#pragma unroll
      for (int u = 0; u < 4; ++u)
        vr[u] = *(const f16x8*)(Vbase + (size_t)vrow * 4096 + kv0 + h2 * 32 + u * 8);
    }
    __syncthreads();  // buf[cur] writes visible; prev readers of buf[nxt] done

    // ---- S^T = K . Q^T ----
    f32x16 s2[2];
    __builtin_amdgcn_s_setprio(1);
#pragma unroll
    for (int t2 = 0; t2 < 2; ++t2) {
#pragma unroll
      for (int r = 0; r < 16; ++r) s2[t2][r] = 0.f;
      int row = t2 * 32 + col;
      const char* kb = (const char*)Ks[cur] + row * 256;
      int sk = swzr(row);
#pragma unroll
      for (int ks = 0; ks < 8; ++ks) {
        f16x8 ak = *(const f16x8*)(kb + ((ks * 32 + hi * 16) ^ sk));
        s2[t2] = MFMA32(ak, bq[ks], s2[t2]);
      }
    }
    __builtin_amdgcn_s_setprio(0);

    // ---- per-lane online softmax (q = col) ----
    float v[16];
#pragma unroll
    for (int r = 0; r < 16; ++r) v[r] = fmaxf(s2[0][r], s2[1][r]);
    float t0 = fmaxf(fmaxf(v[0], v[1]), v[2]);
    float t1 = fmaxf(fmaxf(v[3], v[4]), v[5]);
    float t2 = fmaxf(fmaxf(v[6], v[7]), v[8]);
    float t3 = fmaxf(fmaxf(v[9], v[10]), v[11]);
    float t4 = fmaxf(fmaxf(v[12], v[13]), v[14]);
    float u0 = fmaxf(fmaxf(t0, t1), t2);
    float u1 = fmaxf(fmaxf(t3, t4), v[15]);
    float pm = fmaxf(u0, u1);
    pm = fmaxf(pm, __shfl_xor(pm, 32));
    if (pm > m + 8.f) {  // T13 defer-max
      float sc = __expf(m - pm);
      m = pm;
      nmL = -m * L;
#pragma unroll
      for (int r = 0; r < 16; ++r) lv[r] *= sc;
#pragma unroll
      for (int dt = 0; dt < 4; ++dt)
#pragma unroll
        for (int r = 0; r < 16; ++r) yacc[dt][r] *= sc;
    }
#pragma unroll
    for (int t2i = 0; t2i < 2; ++t2i)
#pragma unroll
      for (int r = 0; r < 16; ++r) s2[t2i][r] = exp2f(fmaf(s2[t2i][r], L, nmL));
#pragma unroll
    for (int r = 0; r < 16; ++r) lv[r] += s2[0][r] + s2[1][r];

    // ---- P -> f16 frags, lane-local (V columns pre-permuted) ----
    f16x8 pfr[4];
#pragma unroll
    for (int t2i = 0; t2i < 2; ++t2i)
#pragma unroll
      for (int k1 = 0; k1 < 2; ++k1) {
        f16x8 f;
#pragma unroll
        for (int c = 0; c < 8; ++c) f[c] = (f16)s2[t2i][8 * k1 + c];
        pfr[t2i * 2 + k1] = f;
      }

    // ---- Y^T += V . P ----
    __builtin_amdgcn_s_setprio(1);
#pragma unroll
    for (int kstep = 0; kstep < 4; ++kstep) {
#pragma unroll
      for (int dt = 0; dt < 4; ++dt) {
        int row = dt * 32 + col;
        f16x8 av = *(const f16x8*)((const char*)Vs[cur] + row * 128 +
                                   ((kstep * 32 + hi * 16) ^ swzr(row)));
        yacc[dt] = MFMA32(av, pfr[kstep], yacc[dt]);
      }
    }
    __builtin_amdgcn_s_setprio(0);

    if (pf) {  // write staged tile t+1 into buf[nxt]
#pragma unroll
      for (int r = 0; r < 4; ++r) {
        int row = r * 16 + krow;
        *(f16x8*)((char*)Ks[nxt] + row * 256 + (kcolb ^ swzr(row))) = kr[r];
      }
      f16x8 c0, c1, c2, c3;
#pragma unroll
      for (int e = 0; e < 4; ++e) {
        c0[e] = vr[0][e];     c0[4 + e] = vr[1][e];
        c1[e] = vr[0][4 + e]; c1[4 + e] = vr[1][4 + e];
        c2[e] = vr[2][e];     c2[4 + e] = vr[3][e];
        c3[e] = vr[2][4 + e]; c3[4 + e] = vr[3][4 + e];
      }
      char* vb = (char*)Vs[nxt] + vrow * 128;
      *(f16x8*)(vb + ((h2 * 64 + 0) ^ sv)) = c0;
      *(f16x8*)(vb + ((h2 * 64 + 16) ^ sv)) = c1;
      *(f16x8*)(vb + ((h2 * 64 + 32) ^ sv)) = c2;
      *(f16x8*)(vb + ((h2 * 64 + 48) ^ sv)) = c3;
    }
  }

  // final l reduce
  float l8[8], l4[4];
#pragma unroll
  for (int i = 0; i < 8; ++i) l8[i] = lv[i] + lv[i + 8];
#pragma unroll
  for (int i = 0; i < 4; ++i) l4[i] = l8[i] + l8[i + 4];
  float l = (l4[0] + l4[1]) + (l4[2] + l4[3]);
  l += __shfl_xor(l, 32);

  int rowG = b * 4096 + qbase + w * 32 + col;
  f16* yo = Yp + ((size_t)half * 32768 + rowG) * 128;
  float inv = 1.0f / l;
#pragma unroll
  for (int dt = 0; dt < 4; ++dt)
#pragma unroll
    for (int a = 0; a < 4; ++a) {
      f16x4 ov = {(f16)(yacc[dt][4 * a] * inv), (f16)(yacc[dt][4 * a + 1] * inv),
                  (f16)(yacc[dt][4 * a + 2] * inv), (f16)(yacc[dt][4 * a + 3] * inv)};
      *(f16x4*)(yo + dt * 32 + a * 8 + hi * 4) = ov;
    }
  if (hi == 0) ml[half * 32768 + rowG] = make_float2(m, l);
}

// ---------------- kernel 3: 2-way combine + epilogue GEMM + bias + residual ----
__global__ __launch_bounds__(256) void epi_k(const f16* __restrict__ Yp,
                                             const float2* __restrict__ ml,
                                             const f16* __restrict__ Wepi,
                                             const float* __restrict__ Wb,
                                             const float* __restrict__ x,
                                             float* __restrict__ out) {
  int b = blockIdx.x >> 6, nt = blockIdx.x & 63;
  int nbase = nt * 64;
  int w = threadIdx.x >> 6, lane = threadIdx.x & 63;
  int lr = lane & 15, lhi = lane >> 4;
  const f16* yb1 = Yp + (size_t)32768 * 128;
  f16x8 by[4][4];
#pragma unroll
  for (int n4 = 0; n4 < 4; ++n4) {
    int row = b * 4096 + nbase + n4 * 16 + lr;
    float2 m0 = ml[row], m1 = ml[32768 + row];
    float mm = fmaxf(m0.x, m1.x);
    float w0 = m0.y * __expf(m0.x - mm), w1 = m1.y * __expf(m1.x - mm);
    float inv = 1.f / (w0 + w1);
    w0 *= inv;
    w1 *= inv;
    size_t rb = (size_t)row * 128;
#pragma unroll
    for (int ks = 0; ks < 4; ++ks) {
      int eo = ks * 32 + lhi * 8;
      f16x8 a0 = *(const f16x8*)(Yp + rb + eo);
      f16x8 a1 = *(const f16x8*)(yb1 + rb + eo);
      f16x8 o;
#pragma unroll
      for (int e = 0; e < 8; ++e) o[e] = (f16)(w0 * (float)a0[e] + w1 * (float)a1[e]);
      by[n4][ks] = o;
    }
  }
#pragma unroll
  for (int ot = 0; ot < 4; ++ot) {
    int o0 = w * 64 + ot * 16;
    const f16x8* wr = (const f16x8*)(Wepi + (size_t)(o0 + lr) * 128);
    f16x8 a[4];
#pragma unroll
    for (int ks = 0; ks < 4; ++ks) a[ks] = wr[ks * 4 + lhi];
#pragma unroll
    for (int n4 = 0; n4 < 4; ++n4) {
      f32x4 acc = {0.f, 0.f, 0.f, 0.f};
#pragma unroll
      for (int ks = 0; ks < 4; ++ks) acc = MFMA16(a[ks], by[n4][ks], acc);
#pragma unroll
      for (int r = 0; r < 4; ++r) {
        int o = o0 + lhi * 4 + r;
        int n = nbase + n4 * 16 + lr;
        size_t idx = ((size_t)b * 256 + o) * 4096 + n;
        out[idx] = x[idx] + Wb[o] + acc[r];
      }
    }
  }
}

extern "C" void kernel_launch(void* const* d_in, const int* in_sizes, int n_in,
                              void* d_out, int out_size, void* d_ws, size_t ws_size,
                              hipStream_t stream) {
  const float* x       = (const float*)d_in[0];
  const float* g_w     = (const float*)d_in[1];
  const float* g_b     = (const float*)d_in[2];
  const float* theta_w = (const float*)d_in[3];
  const float* theta_b = (const float*)d_in[4];
  const float* phi_w   = (const float*)d_in[5];
  const float* phi_b   = (const float*)d_in[6];
  const float* W_w     = (const float*)d_in[7];
  const float* W_b     = (const float*)d_in[8];
  float* out = (float*)d_out;

  f16* Q    = (f16*)d_ws;                       // [8,4096,128] 8MB
  f16* Kk   = Q + (size_t)8 * 4096 * 128;       // 8MB
  f16* Vt   = Kk + (size_t)8 * 4096 * 128;      // 8MB
  f16* Wall = Vt + (size_t)8 * 4096 * 128;      // [384,256]
  f16* Wepi = Wall + 384 * 256;                 // [256,128]
  float2* ml = (float2*)(Wepi + 256 * 128);     // [2][32768] 0.5MB
  f16* Yp   = (f16*)(ml + 2 * 32768);           // [2][32768][128] 16MB (~41MB total)

  wcvt_k<<<512, 256, 0, stream>>>(theta_w, phi_w, g_w, W_w, Wall, Wepi);
  proj_k<<<512, 256, 0, stream>>>(x, Wall, theta_b, phi_b, g_b, Q, Kk, Vt);
  attn_k<<<512, 256, 0, stream>>>(Q, Kk, Vt, Yp, ml);
  epi_k<<<512, 256, 0, stream>>>(Yp, ml, Wepi, W_b, x, out);
}